// Round 2
// baseline (452.942 us; speedup 1.0000x reference)
//
#include <hip/hip_runtime.h>

// Attention block: x_s = softmax(qk^T)[:4096,4096:] @ query @ Wps^T
//                  x_q = softmax(qk^T)[4096:,:4096] @ s     @ Wpq^T
// R12: derived-waits rework of the 256x256 scores GEMM (R11 post-mortem):
//   - plain C++ ds_reads (NO asm lgkmcnt(0) drains) -> compiler emits counted
//     lgkmcnt, MFMAs start after first frags land instead of after all 16
//   - staging of tile t+2 split 4+4 into back phases, into the buffer tile t
//     just finished with (B after P1-end barrier, A after P2-end barrier);
//     prefetch lead 5-6 phases (vs 4), never racing reads (barrier-derived)
//   - one vmcnt(8) per K-tile at P0 (tile t landed, tile t+1's 8 loads stay
//     in flight); vmcnt(0) only on the last tile (8 outstanding would make
//     vmcnt(8) a no-op there)
//   - 3 barriers/K-tile, each required for stage-vs-read ordering
// gemm_qkv + PV keep the verified 256x128 2-barrier structure.

typedef unsigned short u16;
typedef __bf16 bf16x8 __attribute__((ext_vector_type(8)));
typedef float f32x4 __attribute__((ext_vector_type(4)));
typedef unsigned short u16x8 __attribute__((ext_vector_type(8)));

#define DEVI static __device__ __forceinline__

DEVI u16 f2b(float f) {  // fp32 -> bf16 round-to-nearest-even
  unsigned int u = __float_as_uint(f);
  u += 0x7fffu + ((u >> 16) & 1u);
  return (u16)(u >> 16);
}

DEVI float exp2_hw(float x) {  // v_exp_f32: 2^x
  float r;
  asm("v_exp_f32 %0, %1" : "=v"(r) : "v"(x));
  return r;
}

// ---------------- fused prep (unchanged) ----------------
__global__ void prep_all(const float* __restrict__ query, const float* __restrict__ s,
                         const float* __restrict__ tg, const float* __restrict__ w0,
                         const float* __restrict__ w1, const float* __restrict__ w2,
                         u16* __restrict__ cB, u16* __restrict__ sBf,
                         u16* __restrict__ o0, u16* __restrict__ o1,
                         u16* __restrict__ o2, float* __restrict__ rowsum) {
  int b = blockIdx.x;
  if (b >= 6144) {
    int i = (b - 6144) * 1024 + (int)threadIdx.x * 4;
    rowsum[i] = 0.f; rowsum[i + 1] = 0.f; rowsum[i + 2] = 0.f; rowsum[i + 3] = 0.f;
    return;
  }
  if (b < 4096) {
    int base = (b * 256 + threadIdx.x) << 3;
    int row = base >> 10;
    u16x8 o;
    if (row < 4096) {
      float4 a0 = *(const float4*)(s + base);
      float4 a1 = *(const float4*)(s + base + 4);
      float4 b0 = *(const float4*)(tg + base);
      float4 b1 = *(const float4*)(tg + base + 4);
      u16x8 os;
      os[0] = f2b(a0.x); os[1] = f2b(a0.y); os[2] = f2b(a0.z); os[3] = f2b(a0.w);
      os[4] = f2b(a1.x); os[5] = f2b(a1.y); os[6] = f2b(a1.z); os[7] = f2b(a1.w);
      *(u16x8*)(sBf + base) = os;
      o[0] = f2b(a0.x + b0.x); o[1] = f2b(a0.y + b0.y);
      o[2] = f2b(a0.z + b0.z); o[3] = f2b(a0.w + b0.w);
      o[4] = f2b(a1.x + b1.x); o[5] = f2b(a1.y + b1.y);
      o[6] = f2b(a1.z + b1.z); o[7] = f2b(a1.w + b1.w);
    } else {
      int qb = base - 4096 * 1024;
      float4 a0 = *(const float4*)(query + qb);
      float4 a1 = *(const float4*)(query + qb + 4);
      o[0] = f2b(a0.x); o[1] = f2b(a0.y); o[2] = f2b(a0.z); o[3] = f2b(a0.w);
      o[4] = f2b(a1.x); o[5] = f2b(a1.y); o[6] = f2b(a1.z); o[7] = f2b(a1.w);
    }
    *(u16x8*)(cB + base) = o;
  } else {
    const float* in; u16* out; int lb;
    if (b < 5120)      { in = w0; out = o0; lb = b - 4096; }
    else if (b < 5632) { in = w1; out = o1; lb = b - 5120; }
    else               { in = w2; out = o2; lb = b - 5632; }
    int base = (lb * 256 + threadIdx.x) << 3;
    float4 a0 = *(const float4*)(in + base);
    float4 a1 = *(const float4*)(in + base + 4);
    u16x8 o;
    o[0] = f2b(a0.x); o[1] = f2b(a0.y); o[2] = f2b(a0.z); o[3] = f2b(a0.w);
    o[4] = f2b(a1.x); o[5] = f2b(a1.y); o[6] = f2b(a1.z); o[7] = f2b(a1.w);
    *(u16x8*)(out + base) = o;
  }
}

// ====== shared K-loop body for 256x128 tile, 8 waves, wave-tile 64x64 ======
DEVI void kloop(const u16* Ab, const u16* Bb, int lda, int ldb, int K,
                u16* sA, u16* sB, int tid, int wr, int wc, f32x4 (&acc)[4][4]) {
  const int lane = tid & 63;
  const int ar = lane & 15;
  const int sr = tid >> 3;                        // 0..63
  const int scL = (tid & 7) << 3;
  const int scG = ((tid & 7) ^ (sr & 7)) << 3;    // swizzled global col granule

  const int l7 = lane & 7, l16 = lane >> 4;
  const int p0b = (l16 ^ l7) << 4;
  const int offA0 = (wr + ar) * 128 + p0b;
  const int offB0 = (wc + ar) * 128 + p0b;
  const char* sAc = (const char*)sA;
  const char* sBc = (const char*)sB;

  for (int k0 = 0; k0 < K; k0 += 64) {
#pragma unroll
    for (int it = 0; it < 4; ++it) {              // A: 256 rows
      int r = it * 64 + sr;
      __builtin_amdgcn_global_load_lds(
          (__attribute__((address_space(1))) void*)(Ab + (size_t)r * lda + k0 + scG),
          (__attribute__((address_space(3))) void*)(sA + r * 64 + scL), 16, 0, 0);
    }
#pragma unroll
    for (int it = 0; it < 2; ++it) {              // B: 128 rows
      int r = it * 64 + sr;
      __builtin_amdgcn_global_load_lds(
          (__attribute__((address_space(1))) void*)(Bb + (size_t)r * ldb + k0 + scG),
          (__attribute__((address_space(3))) void*)(sB + r * 64 + scL), 16, 0, 0);
    }
    __syncthreads();
#pragma unroll
    for (int half = 0; half < 2; ++half) {
      const int px = half ? 64 : 0;
      bf16x8 af[4], bfr[4];
#pragma unroll
      for (int t = 0; t < 4; ++t)
        af[t] = *(const bf16x8*)(sAc + ((offA0 ^ px) + t * 2048));
#pragma unroll
      for (int t = 0; t < 4; ++t)
        bfr[t] = *(const bf16x8*)(sBc + ((offB0 ^ px) + t * 2048));
#pragma unroll
      for (int tm = 0; tm < 4; ++tm)
#pragma unroll
        for (int tn = 0; tn < 4; ++tn)
          acc[tm][tn] = __builtin_amdgcn_mfma_f32_16x16x32_bf16(
              af[tm], bfr[tn], acc[tm][tn], 0, 0, 0);
    }
    __syncthreads();
  }
}

// ---------------- merged GEMM1 + V'^T (512 thr, 256x128 tile) ----------------
__global__ __launch_bounds__(512)
void gemm_qkv(const u16* __restrict__ cB, const u16* __restrict__ WqkB,
              u16* __restrict__ qks,
              const u16* __restrict__ WpsB, const u16* __restrict__ WpqB,
              const u16* __restrict__ qBf, const u16* __restrict__ sBf,
              u16* __restrict__ VsT, u16* __restrict__ VqT,
              float sq, float sk) {
  __shared__ __align__(16) u16 sA[256 * 64];
  __shared__ __align__(16) u16 sB[128 * 64];
  const int b = blockIdx.x;
  const u16* Ap; const u16* Bp; u16* op;
  int bx, by, ldc;
  bool proj;
  if (b < 512) {
    proj = true;  bx = b & 15; by = b >> 4;
    Ap = cB; Bp = WqkB; op = qks; ldc = 2048;
  } else {
    proj = false;
    int b2 = b - 512;
    int z = b2 >> 7, rem = b2 & 127;
    bx = rem & 31; by = rem >> 5;
    Ap = z ? WpqB : WpsB; Bp = z ? sBf : qBf; op = z ? VqT : VsT; ldc = 4096;
  }
  const int tid = threadIdx.x;
  const int lane = tid & 63;
  const int wave = tid >> 6;           // 0..7
  const int wr = (wave >> 1) * 64;     // 0,64,128,192
  const int wc = (wave & 1) * 64;      // 0,64

  f32x4 acc[4][4];
#pragma unroll
  for (int i = 0; i < 4; ++i)
#pragma unroll
    for (int j = 0; j < 4; ++j) acc[i][j] = f32x4{0.f, 0.f, 0.f, 0.f};

  kloop(Ap + (size_t)(by * 256) * 1024, Bp + (size_t)(bx * 128) * 1024,
        1024, 1024, 1024, sA, sB, tid, wr, wc, acc);

  const int qr = (lane >> 4) * 4;
  const int qc = lane & 15;
#pragma unroll
  for (int tm = 0; tm < 4; ++tm)
#pragma unroll
    for (int r = 0; r < 4; ++r) {
      int row = by * 256 + wr + tm * 16 + qr + r;
#pragma unroll
      for (int tn = 0; tn < 4; ++tn) {
        int col = bx * 128 + wc + tn * 16 + qc;
        float sc = proj ? ((col < 1024) ? sq : sk) : 1.0f;
        op[(size_t)row * ldc + col] = f2b(acc[tm][tn][r] * sc);
      }
    }
}

// ---------------- scores GEMM: 256x256, 8-wave, derived-waits pipeline ------
// Per K-tile (BK=64), quadrant order (0,0),(0,1),(1,0),(1,1):
//  P0: vmcnt(8); barrier; read af0(8)+b0(4); MFMA q(0,0)   [compiler lgkm]
//  P1: read b1(4); MFMA q(0,1); barrier                    [B(t) fully read]
//  P2: stage B(t+2) (4 loads, same buf); read af1(8); MFMA q(1,0); barrier
//  P3: stage A(t+2) (4 loads); MFMA q(1,1)                 [A(t) fully read]
__global__ __launch_bounds__(512)
void gemm_sc(const u16* __restrict__ A, const u16* __restrict__ B,
             u16* __restrict__ Pcq, u16* __restrict__ Pqc,
             float* __restrict__ rowsum) {
  __shared__ __align__(16) u16 lds[2][2][256 * 64];  // [buf][A/B][256 rows x 64]
  const int tid = threadIdx.x;
  const int lane = tid & 63;
  const int wave = tid >> 6;      // 0..7
  const int wm = wave >> 2;       // 0..1 : 128-row half
  const int wn = wave & 3;        // 0..3 : 64-col quarter
  const int bx = blockIdx.x, by = blockIdx.y;

  const int sr = tid >> 3;                      // 0..63
  const int scL = (tid & 7) << 3;
  const int scG = ((tid & 7) ^ (sr & 7)) << 3;  // swizzled source granule

  const int l7 = lane & 7, l16 = lane >> 4;
  const int ar = lane & 15;
  const int p0b = (l16 ^ l7) << 4;
  const int offA0 = (wm * 128 + ar) * 128 + p0b;  // bytes into A region
  const int offB0 = (wn * 64 + ar) * 128 + p0b;   // bytes into B region

  const u16* Ag = A + (size_t)(by * 256) * 2048;
  const u16* Bg = B + (size_t)(bx * 256) * 2048;

// stage one 128-row half of matrix MAT (0=A,1=B) of K-tile at col K0 into BUF
#define STG(BUF, MAT, HALF, K0, SRC)                                          \
  _Pragma("unroll")                                                           \
  for (int l_ = 0; l_ < 2; ++l_) {                                            \
    const int r_ = (HALF) * 128 + l_ * 64 + sr;                               \
    __builtin_amdgcn_global_load_lds(                                         \
        (__attribute__((address_space(1))) void*)((SRC) + (size_t)r_ * 2048 + (K0) + scG), \
        (__attribute__((address_space(3))) void*)(&lds[BUF][MAT][r_ * 64 + scL]), 16, 0, 0); \
  }

#define MFMA_Q(AF, BF, MB, NB)                                                \
  _Pragma("unroll")                                                           \
  for (int tm_ = 0; tm_ < 4; ++tm_) {                                         \
    _Pragma("unroll")                                                         \
    for (int tn_ = 0; tn_ < 2; ++tn_) {                                       \
      _Pragma("unroll")                                                       \
      for (int kh_ = 0; kh_ < 2; ++kh_)                                       \
        acc[(MB) + tm_][(NB) + tn_] =                                         \
            __builtin_amdgcn_mfma_f32_16x16x32_bf16(                          \
                AF[tm_][kh_], BF[tn_][kh_], acc[(MB) + tm_][(NB) + tn_],      \
                0, 0, 0);                                                     \
    }                                                                         \
  }

  f32x4 acc[8][4];
#pragma unroll
  for (int i = 0; i < 8; ++i)
#pragma unroll
    for (int j = 0; j < 4; ++j) acc[i][j] = f32x4{0.f, 0.f, 0.f, 0.f};

  // prologue: tile 0 -> buf0, tile 1 -> buf1 (16 loads/wave in flight)
  STG(0, 0, 0, 0, Ag) STG(0, 0, 1, 0, Ag)
  STG(0, 1, 0, 0, Bg) STG(0, 1, 1, 0, Bg)
  STG(1, 0, 0, 64, Ag) STG(1, 0, 1, 64, Ag)
  STG(1, 1, 0, 64, Bg) STG(1, 1, 1, 64, Bg)

#pragma unroll 1
  for (int kt = 0; kt < 16; ++kt) {
    const int cur = kt & 1;
    const char* sAc = (const char*)lds[cur][0];
    const char* sBc = (const char*)lds[cur][1];

    // ---- P0: tile t landed (t+1's 8 loads stay in flight) ----
    if (kt < 15)
      asm volatile("s_waitcnt vmcnt(8)\n\ts_barrier" ::: "memory");
    else
      asm volatile("s_waitcnt vmcnt(0)\n\ts_barrier" ::: "memory");

    bf16x8 af0[4][2], af1[4][2], b0[2][2], b1[2][2];
#pragma unroll
    for (int t_ = 0; t_ < 4; ++t_) {
      af0[t_][0] = *(const bf16x8*)(sAc + (offA0 + t_ * 2048));
      af0[t_][1] = *(const bf16x8*)(sAc + ((offA0 + t_ * 2048) ^ 64));
    }
#pragma unroll
    for (int t_ = 0; t_ < 2; ++t_) {
      b0[t_][0] = *(const bf16x8*)(sBc + (offB0 + t_ * 2048));
      b0[t_][1] = *(const bf16x8*)(sBc + ((offB0 + t_ * 2048) ^ 64));
    }
    __builtin_amdgcn_s_setprio(1);
    MFMA_Q(af0, b0, 0, 0)
    __builtin_amdgcn_s_setprio(0);

    // ---- P1: quadrant (0,1); B(t) fully read after this ----
#pragma unroll
    for (int t_ = 0; t_ < 2; ++t_) {
      b1[t_][0] = *(const bf16x8*)(sBc + (offB0 + 4096 + t_ * 2048));
      b1[t_][1] = *(const bf16x8*)(sBc + ((offB0 + 4096 + t_ * 2048) ^ 64));
    }
    __builtin_amdgcn_s_setprio(1);
    MFMA_Q(af0, b1, 0, 2)
    __builtin_amdgcn_s_setprio(0);
    asm volatile("s_barrier" ::: "memory");  // all B(t) reads complete

    // ---- P2: stage B(t+2) into vacated B region; quadrant (1,0) ----
    if (kt < 14) {
      STG(cur, 1, 0, (kt + 2) * 64, Bg)
      STG(cur, 1, 1, (kt + 2) * 64, Bg)
    }
#pragma unroll
    for (int t_ = 0; t_ < 4; ++t_) {
      af1[t_][0] = *(const bf16x8*)(sAc + (offA0 + 8192 + t_ * 2048));
      af1[t_][1] = *(const bf16x8*)(sAc + ((offA0 + 8192 + t_ * 2048) ^ 64));
    }
    __builtin_amdgcn_s_setprio(1);
    MFMA_Q(af1, b0, 4, 0)
    __builtin_amdgcn_s_setprio(0);
    asm volatile("s_barrier" ::: "memory");  // all A(t) reads complete

    // ---- P3: stage A(t+2); quadrant (1,1) ----
    if (kt < 14) {
      STG(cur, 0, 0, (kt + 2) * 64, Ag)
      STG(cur, 0, 1, (kt + 2) * 64, Ag)
    }
    __builtin_amdgcn_s_setprio(1);
    MFMA_Q(af1, b1, 4, 2)
    __builtin_amdgcn_s_setprio(0);
  }

  // ---- epilogue: 2^score quadrants + row sums (unchanged) ----
  const int qr = (lane >> 4) * 4;
  const int qc = lane & 15;
  const bool top = (by < 16);
  const bool left = (bx < 16);
  u16* pdst = nullptr;
  if (top && !left) pdst = Pcq;
  if (!top && left) pdst = Pqc;
  const int growb = by * 256 + wm * 128;
  const int rbase = growb - (top ? 0 : 4096);
  const int cbase = bx * 256 + wn * 64 - (left ? 0 : 4096);
#pragma unroll
  for (int i = 0; i < 8; ++i) {
    float e[4][4];
    float rsum[4] = {0.f, 0.f, 0.f, 0.f};
#pragma unroll
    for (int j = 0; j < 4; ++j)
#pragma unroll
      for (int r = 0; r < 4; ++r) {
        e[j][r] = exp2_hw(acc[i][j][r]);  // scores pre-scaled by log2(e)
        rsum[r] += e[j][r];
      }
#pragma unroll
    for (int r = 0; r < 4; ++r) {
      float v = rsum[r];
      v += __shfl_xor(v, 1);
      v += __shfl_xor(v, 2);
      v += __shfl_xor(v, 4);
      v += __shfl_xor(v, 8);
      if ((lane & 15) == 0)
        atomicAdd(&rowsum[growb + i * 16 + qr + r], v);
    }
    if (pdst) {
#pragma unroll
      for (int j = 0; j < 4; ++j)
#pragma unroll
        for (int r = 0; r < 4; ++r) {
          int row = rbase + i * 16 + qr + r;
          pdst[(size_t)row * 4096 + cbase + j * 16 + qc] = f2b(e[j][r]);
        }
    }
  }
#undef STG
#undef MFMA_Q
}

// ---------------- PV GEMM (EPI4), 256x128 tile (unchanged) ----------------
template <int EPI>
__global__ __launch_bounds__(512)
void gemm_bt(const u16* __restrict__ A, const u16* __restrict__ A1,
             const u16* __restrict__ B, const u16* __restrict__ B1,
             int lda, int ldb, int K, int ldc,
             float* __restrict__ outf, float* __restrict__ outf1,
             const float* __restrict__ rs, const float* __restrict__ rs1,
             u16* __restrict__ Pcq, u16* __restrict__ Pqc,
             float* __restrict__ rowsum) {
  __shared__ __align__(16) u16 sA[256 * 64];
  __shared__ __align__(16) u16 sB[128 * 64];
  const int tid = threadIdx.x;
  const int lane = tid & 63;
  const int wave = tid >> 6;
  const int wr = (wave >> 1) * 64;
  const int wc = (wave & 1) * 64;
  const int by = blockIdx.y, bx = blockIdx.x;
  const int z = blockIdx.z;

  f32x4 acc[4][4];
#pragma unroll
  for (int i = 0; i < 4; ++i)
#pragma unroll
    for (int j = 0; j < 4; ++j) acc[i][j] = f32x4{0.f, 0.f, 0.f, 0.f};

  kloop((z ? A1 : A) + (size_t)(by * 256) * lda,
        (z ? B1 : B) + (size_t)(bx * 128) * ldb,
        lda, ldb, K, sA, sB, tid, wr, wc, acc);

  const int qr = (lane >> 4) * 4;
  const int qc = lane & 15;

  if constexpr (EPI == 4) {
    float* of = z ? outf1 : outf;
    const float* rsz = z ? rs1 : rs;
#pragma unroll
    for (int tm = 0; tm < 4; ++tm)
#pragma unroll
      for (int r = 0; r < 4; ++r) {
        int row = by * 256 + wr + tm * 16 + qr + r;
        float inv = 1.0f / rsz[row];
#pragma unroll
        for (int tn = 0; tn < 4; ++tn) {
          int col = bx * 128 + wc + tn * 16 + qc;
          of[(size_t)row * ldc + col] = acc[tm][tn][r] * inv;
        }
      }
  }
}

// ---------------- launcher ----------------

extern "C" void kernel_launch(void* const* d_in, const int* in_sizes, int n_in,
                              void* d_out, int out_size, void* d_ws, size_t ws_size,
                              hipStream_t stream) {
  (void)in_sizes; (void)n_in; (void)out_size; (void)ws_size;
  const float* query = (const float*)d_in[0];
  const float* s     = (const float*)d_in[1];
  const float* tg    = (const float*)d_in[2];
  const float* Wqkv  = (const float*)d_in[3];
  const float* Wps   = (const float*)d_in[4];
  const float* Wpq   = (const float*)d_in[5];
  float* out = (float*)d_out;

  char* ws = (char*)d_ws;
  u16* cB     = (u16*)ws; ws += (size_t)8192 * 1024 * 2;   // [s+tg ; query] bf16
  u16* sBf    = (u16*)ws; ws += (size_t)4096 * 1024 * 2;   // s bf16
  u16* qks    = (u16*)ws; ws += (size_t)8192 * 2048 * 2;   // [q*SCALE*LOG2E | k*SCALE]
  u16* WqkB   = (u16*)ws; ws += (size_t)2048 * 1024 * 2;
  u16* WpsB   = (u16*)ws; ws += (size_t)1024 * 1024 * 2;
  u16* WpqB   = (u16*)ws; ws += (size_t)1024 * 1024 * 2;
  u16* VsT    = (u16*)ws; ws += (size_t)1024 * 4096 * 2;   // Wps@query^T
  u16* VqT    = (u16*)ws; ws += (size_t)1024 * 4096 * 2;   // Wpq@s^T
  u16* Pcq    = (u16*)ws; ws += (size_t)4096 * 4096 * 2;
  u16* Pqc    = (u16*)ws; ws += (size_t)4096 * 4096 * 2;
  float* rowsum = (float*)ws;  // 8192 floats

  const u16* qBf = cB + (size_t)4096 * 1024;  // query bf16 rows of cB

  const float SCALE = 0.17677669529663687f;   // 1024^-0.25
  const float LOG2E = 1.4426950408889634f;

  prep_all<<<6152, 256, 0, stream>>>(query, s, tg, Wqkv, Wps, Wpq,
                                     cB, sBf, WqkB, WpsB, WpqB, rowsum);
  // merged GEMM1 + V'^T pair (768 blocks of 512 thr)
  gemm_qkv<<<768, 512, 0, stream>>>(cB, WqkB, qks, WpsB, WpqB, qBf, sBf,
                                    VsT, VqT, SCALE * LOG2E, SCALE);
  // GEMM2: scores (8192x8192) -> 2^score quadrants (bf16) + row sums
  gemm_sc<<<dim3(32, 32), 512, 0, stream>>>(qks, qks + 1024, Pcq, Pqc, rowsum);
  // PV (z-batched), fp32 straight to d_out
  gemm_bt<4><<<dim3(8, 16, 2), 512, 0, stream>>>(
      Pcq, Pqc, VsT, VqT, 4096, 4096, 4096, 1024,
      out, out + (size_t)4096 * 1024, rowsum, rowsum + 4096,
      nullptr, nullptr, nullptr);
}

// Round 3
// 421.060 us; speedup vs baseline: 1.0757x; 1.0757x over previous
//
#include <hip/hip_runtime.h>

// Attention block: x_s = softmax(qk^T)[:4096,4096:] @ query @ Wps^T
//                  x_q = softmax(qk^T)[4096:,:4096] @ s     @ Wpq^T
// R13: revert scores to the verified R10 2-barrier 256x128 structure (two
// 8-phase ports both lost to 3-blocks/CU TLP; m232 failure mode confirmed).
// New this round, orthogonal to the K-loop:
//   - T1 XCD-chunked blockIdx swizzle on scores / qkv / PV (all grids %8==0,
//     bijective): resident A-panels per XCD drop ~12 -> ~1.5 (6MB -> 1MB,
//     fits 4MiB L2).
//   - PV switched from 256x128/8-wave (grid 256 = 1 block/CU, zero
//     inter-block overlap) to the verified m97 config: 128x128, 4 waves,
//     grid 512 = 2 blocks/CU with decoupled barriers (m103: 912 TF @ K=4096).

typedef unsigned short u16;
typedef __bf16 bf16x8 __attribute__((ext_vector_type(8)));
typedef float f32x4 __attribute__((ext_vector_type(4)));
typedef unsigned short u16x8 __attribute__((ext_vector_type(8)));

#define DEVI static __device__ __forceinline__

DEVI u16 f2b(float f) {  // fp32 -> bf16 round-to-nearest-even
  unsigned int u = __float_as_uint(f);
  u += 0x7fffu + ((u >> 16) & 1u);
  return (u16)(u >> 16);
}

DEVI float exp2_hw(float x) {  // v_exp_f32: 2^x
  float r;
  asm("v_exp_f32 %0, %1" : "=v"(r) : "v"(x));
  return r;
}

// ---------------- fused prep (unchanged) ----------------
__global__ void prep_all(const float* __restrict__ query, const float* __restrict__ s,
                         const float* __restrict__ tg, const float* __restrict__ w0,
                         const float* __restrict__ w1, const float* __restrict__ w2,
                         u16* __restrict__ cB, u16* __restrict__ sBf,
                         u16* __restrict__ o0, u16* __restrict__ o1,
                         u16* __restrict__ o2, float* __restrict__ rowsum) {
  int b = blockIdx.x;
  if (b >= 6144) {
    int i = (b - 6144) * 1024 + (int)threadIdx.x * 4;
    rowsum[i] = 0.f; rowsum[i + 1] = 0.f; rowsum[i + 2] = 0.f; rowsum[i + 3] = 0.f;
    return;
  }
  if (b < 4096) {
    int base = (b * 256 + threadIdx.x) << 3;
    int row = base >> 10;
    u16x8 o;
    if (row < 4096) {
      float4 a0 = *(const float4*)(s + base);
      float4 a1 = *(const float4*)(s + base + 4);
      float4 b0 = *(const float4*)(tg + base);
      float4 b1 = *(const float4*)(tg + base + 4);
      u16x8 os;
      os[0] = f2b(a0.x); os[1] = f2b(a0.y); os[2] = f2b(a0.z); os[3] = f2b(a0.w);
      os[4] = f2b(a1.x); os[5] = f2b(a1.y); os[6] = f2b(a1.z); os[7] = f2b(a1.w);
      *(u16x8*)(sBf + base) = os;
      o[0] = f2b(a0.x + b0.x); o[1] = f2b(a0.y + b0.y);
      o[2] = f2b(a0.z + b0.z); o[3] = f2b(a0.w + b0.w);
      o[4] = f2b(a1.x + b1.x); o[5] = f2b(a1.y + b1.y);
      o[6] = f2b(a1.z + b1.z); o[7] = f2b(a1.w + b1.w);
    } else {
      int qb = base - 4096 * 1024;
      float4 a0 = *(const float4*)(query + qb);
      float4 a1 = *(const float4*)(query + qb + 4);
      o[0] = f2b(a0.x); o[1] = f2b(a0.y); o[2] = f2b(a0.z); o[3] = f2b(a0.w);
      o[4] = f2b(a1.x); o[5] = f2b(a1.y); o[6] = f2b(a1.z); o[7] = f2b(a1.w);
    }
    *(u16x8*)(cB + base) = o;
  } else {
    const float* in; u16* out; int lb;
    if (b < 5120)      { in = w0; out = o0; lb = b - 4096; }
    else if (b < 5632) { in = w1; out = o1; lb = b - 5120; }
    else               { in = w2; out = o2; lb = b - 5632; }
    int base = (lb * 256 + threadIdx.x) << 3;
    float4 a0 = *(const float4*)(in + base);
    float4 a1 = *(const float4*)(in + base + 4);
    u16x8 o;
    o[0] = f2b(a0.x); o[1] = f2b(a0.y); o[2] = f2b(a0.z); o[3] = f2b(a0.w);
    o[4] = f2b(a1.x); o[5] = f2b(a1.y); o[6] = f2b(a1.z); o[7] = f2b(a1.w);
    *(u16x8*)(out + base) = o;
  }
}

// ====== K-loop, 256x128 tile, 512 thr (8 waves), wave-tile 64x64 ======
DEVI void kloop(const u16* Ab, const u16* Bb, int lda, int ldb, int K,
                u16* sA, u16* sB, int tid, int wr, int wc, f32x4 (&acc)[4][4]) {
  const int lane = tid & 63;
  const int ar = lane & 15;
  const int sr = tid >> 3;                        // 0..63
  const int scL = (tid & 7) << 3;
  const int scG = ((tid & 7) ^ (sr & 7)) << 3;    // swizzled global col granule

  const int l7 = lane & 7, l16 = lane >> 4;
  const int p0b = (l16 ^ l7) << 4;
  const int offA0 = (wr + ar) * 128 + p0b;
  const int offB0 = (wc + ar) * 128 + p0b;
  const char* sAc = (const char*)sA;
  const char* sBc = (const char*)sB;

  for (int k0 = 0; k0 < K; k0 += 64) {
#pragma unroll
    for (int it = 0; it < 4; ++it) {              // A: 256 rows
      int r = it * 64 + sr;
      __builtin_amdgcn_global_load_lds(
          (__attribute__((address_space(1))) void*)(Ab + (size_t)r * lda + k0 + scG),
          (__attribute__((address_space(3))) void*)(sA + r * 64 + scL), 16, 0, 0);
    }
#pragma unroll
    for (int it = 0; it < 2; ++it) {              // B: 128 rows
      int r = it * 64 + sr;
      __builtin_amdgcn_global_load_lds(
          (__attribute__((address_space(1))) void*)(Bb + (size_t)r * ldb + k0 + scG),
          (__attribute__((address_space(3))) void*)(sB + r * 64 + scL), 16, 0, 0);
    }
    __syncthreads();
#pragma unroll
    for (int half = 0; half < 2; ++half) {
      const int px = half ? 64 : 0;
      bf16x8 af[4], bfr[4];
#pragma unroll
      for (int t = 0; t < 4; ++t)
        af[t] = *(const bf16x8*)(sAc + ((offA0 ^ px) + t * 2048));
#pragma unroll
      for (int t = 0; t < 4; ++t)
        bfr[t] = *(const bf16x8*)(sBc + ((offB0 ^ px) + t * 2048));
#pragma unroll
      for (int tm = 0; tm < 4; ++tm)
#pragma unroll
        for (int tn = 0; tn < 4; ++tn)
          acc[tm][tn] = __builtin_amdgcn_mfma_f32_16x16x32_bf16(
              af[tm], bfr[tn], acc[tm][tn], 0, 0, 0);
    }
    __syncthreads();
  }
}

// ====== K-loop, 128x128 tile, 256 thr (4 waves), wave-tile 64x64 ======
DEVI void kloop128(const u16* Ab, const u16* Bb, int lda, int ldb, int K,
                   u16* sA, u16* sB, int tid, int wr, int wc, f32x4 (&acc)[4][4]) {
  const int lane = tid & 63;
  const int ar = lane & 15;
  const int sr = tid >> 3;                        // 0..31
  const int scL = (tid & 7) << 3;
  const int scG = ((tid & 7) ^ (sr & 7)) << 3;

  const int l7 = lane & 7, l16 = lane >> 4;
  const int p0b = (l16 ^ l7) << 4;
  const int offA0 = (wr + ar) * 128 + p0b;
  const int offB0 = (wc + ar) * 128 + p0b;
  const char* sAc = (const char*)sA;
  const char* sBc = (const char*)sB;

  for (int k0 = 0; k0 < K; k0 += 64) {
#pragma unroll
    for (int it = 0; it < 4; ++it) {              // A: 128 rows, 32/iter
      int r = it * 32 + sr;
      __builtin_amdgcn_global_load_lds(
          (__attribute__((address_space(1))) void*)(Ab + (size_t)r * lda + k0 + scG),
          (__attribute__((address_space(3))) void*)(sA + r * 64 + scL), 16, 0, 0);
    }
#pragma unroll
    for (int it = 0; it < 4; ++it) {              // B: 128 rows
      int r = it * 32 + sr;
      __builtin_amdgcn_global_load_lds(
          (__attribute__((address_space(1))) void*)(Bb + (size_t)r * ldb + k0 + scG),
          (__attribute__((address_space(3))) void*)(sB + r * 64 + scL), 16, 0, 0);
    }
    __syncthreads();
#pragma unroll
    for (int half = 0; half < 2; ++half) {
      const int px = half ? 64 : 0;
      bf16x8 af[4], bfr[4];
#pragma unroll
      for (int t = 0; t < 4; ++t)
        af[t] = *(const bf16x8*)(sAc + ((offA0 ^ px) + t * 2048));
#pragma unroll
      for (int t = 0; t < 4; ++t)
        bfr[t] = *(const bf16x8*)(sBc + ((offB0 ^ px) + t * 2048));
#pragma unroll
      for (int tm = 0; tm < 4; ++tm)
#pragma unroll
        for (int tn = 0; tn < 4; ++tn)
          acc[tm][tn] = __builtin_amdgcn_mfma_f32_16x16x32_bf16(
              af[tm], bfr[tn], acc[tm][tn], 0, 0, 0);
    }
    __syncthreads();
  }
}

// ---------------- merged GEMM1 + V'^T (512 thr, 256x128 tile) ----------------
__global__ __launch_bounds__(512)
void gemm_qkv(const u16* __restrict__ cB, const u16* __restrict__ WqkB,
              u16* __restrict__ qks,
              const u16* __restrict__ WpsB, const u16* __restrict__ WpqB,
              const u16* __restrict__ qBf, const u16* __restrict__ sBf,
              u16* __restrict__ VsT, u16* __restrict__ VqT,
              float sq, float sk) {
  __shared__ __align__(16) u16 sA[256 * 64];
  __shared__ __align__(16) u16 sB[128 * 64];
  int b = blockIdx.x;
  b = (b & 7) * 96 + (b >> 3);         // XCD-chunked swizzle (768 = 8*96)
  const u16* Ap; const u16* Bp; u16* op;
  int bx, by, ldc;
  bool proj;
  if (b < 512) {
    proj = true;  bx = b & 15; by = b >> 4;
    Ap = cB; Bp = WqkB; op = qks; ldc = 2048;
  } else {
    proj = false;
    int b2 = b - 512;
    int z = b2 >> 7, rem = b2 & 127;
    bx = rem & 31; by = rem >> 5;
    Ap = z ? WpqB : WpsB; Bp = z ? sBf : qBf; op = z ? VqT : VsT; ldc = 4096;
  }
  const int tid = threadIdx.x;
  const int lane = tid & 63;
  const int wave = tid >> 6;           // 0..7
  const int wr = (wave >> 1) * 64;     // 0,64,128,192
  const int wc = (wave & 1) * 64;      // 0,64

  f32x4 acc[4][4];
#pragma unroll
  for (int i = 0; i < 4; ++i)
#pragma unroll
    for (int j = 0; j < 4; ++j) acc[i][j] = f32x4{0.f, 0.f, 0.f, 0.f};

  kloop(Ap + (size_t)(by * 256) * 1024, Bp + (size_t)(bx * 128) * 1024,
        1024, 1024, 1024, sA, sB, tid, wr, wc, acc);

  const int qr = (lane >> 4) * 4;
  const int qc = lane & 15;
#pragma unroll
  for (int tm = 0; tm < 4; ++tm)
#pragma unroll
    for (int r = 0; r < 4; ++r) {
      int row = by * 256 + wr + tm * 16 + qr + r;
#pragma unroll
      for (int tn = 0; tn < 4; ++tn) {
        int col = bx * 128 + wc + tn * 16 + qc;
        float sc = proj ? ((col < 1024) ? sq : sk) : 1.0f;
        op[(size_t)row * ldc + col] = f2b(acc[tm][tn][r] * sc);
      }
    }
}

// ---------------- scores GEMM (R10 structure + XCD swizzle) ----------------
// 1D grid 2048; swz chunked across XCDs; bx in [0,64) (128-col tiles),
// by in [0,32) (256-row tiles).
__global__ __launch_bounds__(512)
void gemm_scores(const u16* __restrict__ qks, u16* __restrict__ Pcq,
                 u16* __restrict__ Pqc, float* __restrict__ rowsum) {
  __shared__ __align__(16) u16 sA[256 * 64];
  __shared__ __align__(16) u16 sB[128 * 64];
  const int tid = threadIdx.x;
  const int lane = tid & 63;
  const int wave = tid >> 6;
  const int wr = (wave >> 1) * 64;
  const int wc = (wave & 1) * 64;
  int b = blockIdx.x;
  int swz = (b & 7) * 256 + (b >> 3);  // 2048 = 8*256, bijective
  const int bx = swz & 63;
  const int by = swz >> 6;

  f32x4 acc[4][4];
#pragma unroll
  for (int i = 0; i < 4; ++i)
#pragma unroll
    for (int j = 0; j < 4; ++j) acc[i][j] = f32x4{0.f, 0.f, 0.f, 0.f};

  kloop(qks + (size_t)(by * 256) * 2048,
        qks + 1024 + (size_t)(bx * 128) * 2048,
        2048, 2048, 1024, sA, sB, tid, wr, wc, acc);

  const int qr = (lane >> 4) * 4;
  const int qc = lane & 15;
  const bool top = (by < 16);
  const bool left = (bx < 32);
  u16* pdst = nullptr;
  if (top && !left) pdst = Pcq;
  if (!top && left) pdst = Pqc;
  const int growb = by * 256 + wr;
  const int rbase = growb - (top ? 0 : 4096);
  const int cbase = bx * 128 + wc - (left ? 0 : 4096);
#pragma unroll
  for (int tm = 0; tm < 4; ++tm) {
    float e[4][4];
    float rsum[4] = {0.f, 0.f, 0.f, 0.f};
#pragma unroll
    for (int tn = 0; tn < 4; ++tn)
#pragma unroll
      for (int r = 0; r < 4; ++r) {
        e[tn][r] = exp2_hw(acc[tm][tn][r]);  // scores pre-scaled by log2(e)
        rsum[r] += e[tn][r];
      }
#pragma unroll
    for (int r = 0; r < 4; ++r) {
      float v = rsum[r];
      v += __shfl_xor(v, 1);
      v += __shfl_xor(v, 2);
      v += __shfl_xor(v, 4);
      v += __shfl_xor(v, 8);
      if ((lane & 15) == 0)
        atomicAdd(&rowsum[growb + tm * 16 + qr + r], v);
    }
    if (pdst) {
#pragma unroll
      for (int tn = 0; tn < 4; ++tn)
#pragma unroll
        for (int r = 0; r < 4; ++r) {
          int row = rbase + tm * 16 + qr + r;
          pdst[(size_t)row * 4096 + cbase + tn * 16 + qc] = f2b(e[tn][r]);
        }
    }
  }
}

// ---------------- PV GEMM: 128x128, 4 waves, 2 blocks/CU ----------------
__global__ __launch_bounds__(256)
void gemm_pv(const u16* __restrict__ Pcq, const u16* __restrict__ Pqc,
             const u16* __restrict__ VsT, const u16* __restrict__ VqT,
             const float* __restrict__ rowsum,
             float* __restrict__ out0, float* __restrict__ out1) {
  __shared__ __align__(16) u16 sA[128 * 64];
  __shared__ __align__(16) u16 sB[128 * 64];
  const int tid = threadIdx.x;
  const int lane = tid & 63;
  const int wave = tid >> 6;            // 0..3
  const int wr = (wave >> 1) * 64;      // 0,64
  const int wc = (wave & 1) * 64;       // 0,64
  int b = blockIdx.x;
  int swz = (b & 7) * 64 + (b >> 3);    // 512 = 8*64, bijective
  const int z = swz >> 8;
  const int rem = swz & 255;
  const int by = rem >> 3;              // 0..31 (128-row tiles)
  const int bx = rem & 7;               // 0..7  (128-col tiles)

  f32x4 acc[4][4];
#pragma unroll
  for (int i = 0; i < 4; ++i)
#pragma unroll
    for (int j = 0; j < 4; ++j) acc[i][j] = f32x4{0.f, 0.f, 0.f, 0.f};

  kloop128((z ? Pqc : Pcq) + (size_t)(by * 128) * 4096,
           (z ? VqT : VsT) + (size_t)(bx * 128) * 4096,
           4096, 4096, 4096, sA, sB, tid, wr, wc, acc);

  const int qr = (lane >> 4) * 4;
  const int qc = lane & 15;
  float* of = z ? out1 : out0;
  const float* rsz = rowsum + z * 4096;
#pragma unroll
  for (int tm = 0; tm < 4; ++tm)
#pragma unroll
    for (int r = 0; r < 4; ++r) {
      int row = by * 128 + wr + tm * 16 + qr + r;
      float inv = 1.0f / rsz[row];
#pragma unroll
      for (int tn = 0; tn < 4; ++tn) {
        int col = bx * 128 + wc + tn * 16 + qc;
        of[(size_t)row * 1024 + col] = acc[tm][tn][r] * inv;
      }
    }
}

// ---------------- launcher ----------------

extern "C" void kernel_launch(void* const* d_in, const int* in_sizes, int n_in,
                              void* d_out, int out_size, void* d_ws, size_t ws_size,
                              hipStream_t stream) {
  (void)in_sizes; (void)n_in; (void)out_size; (void)ws_size;
  const float* query = (const float*)d_in[0];
  const float* s     = (const float*)d_in[1];
  const float* tg    = (const float*)d_in[2];
  const float* Wqkv  = (const float*)d_in[3];
  const float* Wps   = (const float*)d_in[4];
  const float* Wpq   = (const float*)d_in[5];
  float* out = (float*)d_out;

  char* ws = (char*)d_ws;
  u16* cB     = (u16*)ws; ws += (size_t)8192 * 1024 * 2;   // [s+tg ; query] bf16
  u16* sBf    = (u16*)ws; ws += (size_t)4096 * 1024 * 2;   // s bf16
  u16* qks    = (u16*)ws; ws += (size_t)8192 * 2048 * 2;   // [q*SCALE*LOG2E | k*SCALE]
  u16* WqkB   = (u16*)ws; ws += (size_t)2048 * 1024 * 2;
  u16* WpsB   = (u16*)ws; ws += (size_t)1024 * 1024 * 2;
  u16* WpqB   = (u16*)ws; ws += (size_t)1024 * 1024 * 2;
  u16* VsT    = (u16*)ws; ws += (size_t)1024 * 4096 * 2;   // Wps@query^T
  u16* VqT    = (u16*)ws; ws += (size_t)1024 * 4096 * 2;   // Wpq@s^T
  u16* Pcq    = (u16*)ws; ws += (size_t)4096 * 4096 * 2;
  u16* Pqc    = (u16*)ws; ws += (size_t)4096 * 4096 * 2;
  float* rowsum = (float*)ws;  // 8192 floats

  const u16* qBf = cB + (size_t)4096 * 1024;  // query bf16 rows of cB

  const float SCALE = 0.17677669529663687f;   // 1024^-0.25
  const float LOG2E = 1.4426950408889634f;

  prep_all<<<6152, 256, 0, stream>>>(query, s, tg, Wqkv, Wps, Wpq,
                                     cB, sBf, WqkB, WpsB, WpqB, rowsum);
  // merged GEMM1 + V'^T pair (768 blocks of 512 thr)
  gemm_qkv<<<768, 512, 0, stream>>>(cB, WqkB, qks, WpsB, WpqB, qBf, sBf,
                                    VsT, VqT, SCALE * LOG2E, SCALE);
  // GEMM2: scores (8192x8192) -> 2^score quadrants (bf16) + row sums
  gemm_scores<<<2048, 512, 0, stream>>>(qks, Pcq, Pqc, rowsum);
  // PV (z in swizzle), fp32 straight to d_out
  gemm_pv<<<512, 256, 0, stream>>>(Pcq, Pqc, VsT, VqT, rowsum,
                                   out, out + (size_t)4096 * 1024);
}